// Round 1
// baseline (756.434 us; speedup 1.0000x reference)
//
#include <hip/hip_runtime.h>
#include <hip/hip_fp16.h>

// Problem constants
#define BATCH 16384
#define DIM   256
#define KC    3000
#define KCPAD 3072

typedef __bf16 bf16x8 __attribute__((ext_vector_type(8)));
typedef float  floatx4 __attribute__((ext_vector_type(4)));

__device__ inline float blk_sum(float v, float* s4) {
#pragma unroll
  for (int o = 32; o; o >>= 1) v += __shfl_down(v, o, 64);
  int t = threadIdx.x;
  __syncthreads();
  if ((t & 63) == 0) s4[t >> 6] = v;
  __syncthreads();
  return s4[0] + s4[1] + s4[2] + s4[3];
}

__device__ inline float blk_max(float v, float* s4) {
#pragma unroll
  for (int o = 32; o; o >>= 1) v = fmaxf(v, __shfl_down(v, o, 64));
  int t = threadIdx.x;
  __syncthreads();
  if ((t & 63) == 0) s4[t >> 6] = v;
  __syncthreads();
  return fmaxf(fmaxf(s4[0], s4[1]), fmaxf(s4[2], s4[3]));
}

// L2-normalize rows of x [R x 256] -> bf16 out [gridDim.x x 256]; rows >= R zero-filled.
__global__ __launch_bounds__(256) void normalize_rows(const float* __restrict__ x,
                                                      __bf16* __restrict__ out, int R) {
  __shared__ float s4[4];
  int row = blockIdx.x;
  int t = threadIdx.x;
  float v = 0.f;
  if (row < R) v = x[(size_t)row * DIM + t];
  float ss = blk_sum(v * v, s4);
  float inv = 1.f / fmaxf(sqrtf(ss), 1e-12f);
  out[(size_t)row * DIM + t] = (__bf16)(v * inv);
}

// S[m][n] = sum_k A[m][k] * Bm[n][k];  A [16384x256], Bm [3072x256] (B^T layout),
// S fp16 [16384 x 3000]. 128x128 tile per block, 4 waves, 16x16x32 MFMA.
__global__ __launch_bounds__(256) void gemm_bf16(const __bf16* __restrict__ A,
                                                 const __bf16* __restrict__ Bm,
                                                 __half* __restrict__ S) {
  __shared__ __align__(16) __bf16 As[128 * 32];
  __shared__ __align__(16) __bf16 Bs[128 * 32];
  const int tid = threadIdx.x;
  const int bm = blockIdx.x * 128;
  const int bn = blockIdx.y * 128;
  const int wid = tid >> 6;
  const int lane = tid & 63;
  const int wm = (wid >> 1) * 64;
  const int wn = (wid & 1) * 64;
  const int frow = lane & 15;
  const int fk = (lane >> 4) * 8;

  floatx4 acc[4][4] = {};

  for (int kt = 0; kt < DIM; kt += 32) {
    __syncthreads();
#pragma unroll
    for (int c = 0; c < 2; ++c) {
      int idx = tid + c * 256;     // 0..511 chunks of 16B
      int r = idx >> 2;
      int o = (idx & 3) * 8;
      *reinterpret_cast<int4*>(&As[r * 32 + o]) =
          *reinterpret_cast<const int4*>(A + (size_t)(bm + r) * DIM + kt + o);
      *reinterpret_cast<int4*>(&Bs[r * 32 + o]) =
          *reinterpret_cast<const int4*>(Bm + (size_t)(bn + r) * DIM + kt + o);
    }
    __syncthreads();
    bf16x8 af[4], bfr[4];
#pragma unroll
    for (int i = 0; i < 4; ++i)
      af[i] = *reinterpret_cast<const bf16x8*>(&As[(wm + i * 16 + frow) * 32 + fk]);
#pragma unroll
    for (int j = 0; j < 4; ++j)
      bfr[j] = *reinterpret_cast<const bf16x8*>(&Bs[(wn + j * 16 + frow) * 32 + fk]);
#pragma unroll
    for (int i = 0; i < 4; ++i)
#pragma unroll
      for (int j = 0; j < 4; ++j)
        acc[i][j] = __builtin_amdgcn_mfma_f32_16x16x32_bf16(af[i], bfr[j], acc[i][j], 0, 0, 0);
  }

  const int rgrp = (lane >> 4) * 4;   // C/D: row = (lane>>4)*4 + reg, col = lane&15
  const int cl = lane & 15;
#pragma unroll
  for (int i = 0; i < 4; ++i) {
#pragma unroll
    for (int j = 0; j < 4; ++j) {
      int colb = bn + wn + j * 16 + cl;
      if (colb < KC) {
#pragma unroll
        for (int r = 0; r < 4; ++r) {
          int rowb = bm + wm + i * 16 + rgrp + r;
          S[(size_t)rowb * KC + colb] = __float2half(acc[i][j][r]);
        }
      }
    }
  }
}

// out[col] += sum_r exp(S[r][col]*20) * (w ? w[r] : 1)  over a 128-row chunk
__global__ __launch_bounds__(256) void colsum_exp(const __half* __restrict__ S,
                                                  const float* __restrict__ w,
                                                  float* __restrict__ out) {
  int col = blockIdx.x * 256 + threadIdx.x;
  if (col >= KC) return;
  int r0 = blockIdx.y * 128;
  float acc = 0.f;
  if (w) {
    for (int r = r0; r < r0 + 128; ++r)
      acc += __expf(__half2float(S[(size_t)r * KC + col]) * 20.f) * w[r];
  } else {
    for (int r = r0; r < r0 + 128; ++r)
      acc += __expf(__half2float(S[(size_t)r * KC + col]) * 20.f);
  }
  atomicAdd(&out[col], acc);
}

// out[row] = sum_k exp(S[row][k]*20) * u[k]
__global__ __launch_bounds__(256) void rowsum_exp(const __half* __restrict__ S,
                                                  const float* __restrict__ u,
                                                  float* __restrict__ out) {
  __shared__ float s4[4];
  int row = blockIdx.x;
  float acc = 0.f;
  for (int k = threadIdx.x; k < KC; k += 256)
    acc += __expf(__half2float(S[(size_t)row * KC + k]) * 20.f) * u[k];
  float tot = blk_sum(acc, s4);
  if (threadIdx.x == 0) out[row] = tot;
}

// out[row] = logsumexp_k (S[row][k]*10)
__global__ __launch_bounds__(256) void row_lse(const __half* __restrict__ S,
                                               float* __restrict__ out) {
  __shared__ float s4[4];
  int row = blockIdx.x;
  float mx = -1e30f;
  for (int k = threadIdx.x; k < KC; k += 256)
    mx = fmaxf(mx, __half2float(S[(size_t)row * KC + k]) * 10.f);
  float m = blk_max(mx, s4);
  float acc = 0.f;
  for (int k = threadIdx.x; k < KC; k += 256)
    acc += __expf(__half2float(S[(size_t)row * KC + k]) * 10.f - m);
  float tot = blk_sum(acc, s4);
  if (threadIdx.x == 0) out[row] = m + logf(tot);
}

__global__ void vrecip(const float* __restrict__ in, float* __restrict__ out,
                       int n, float scale) {
  int i = blockIdx.x * 256 + threadIdx.x;
  if (i < n) out[i] = 1.f / (scale * in[i]);
}

// Fused KL for both losses. code = B*exp(s*20)*u[k]*v[b]; logp = s_other*10 - lse_other[b]
__global__ __launch_bounds__(256) void kl_kernel(
    const __half* __restrict__ Sk, const __half* __restrict__ Sq,
    const float* __restrict__ uk, const float* __restrict__ vk,
    const float* __restrict__ uq, const float* __restrict__ vq,
    const float* __restrict__ lseq, const float* __restrict__ lsek,
    float* __restrict__ accOut) {
  __shared__ float vks[256], vqs[256], lvks[256], lvqs[256], lsqs[256], lsks[256];
  __shared__ float s4[4];
  int tx = threadIdx.x;
  int r0 = blockIdx.y * 256;
  {
    int r = r0 + tx;
    float a = vk[r], b = vq[r];
    vks[tx] = a; vqs[tx] = b;
    lvks[tx] = logf(a); lvqs[tx] = logf(b);
    lsqs[tx] = lseq[r]; lsks[tx] = lsek[r];
  }
  __syncthreads();
  int col = blockIdx.x * 256 + tx;
  float acc = 0.f;
  if (col < KC) {
    float cuk = uk[col], cuq = uq[col];
    float luk = logf(cuk), luq = logf(cuq);
    const float logB = logf(16384.f);
    for (int i = 0; i < 256; ++i) {
      size_t idx = (size_t)(r0 + i) * KC + col;
      float sk = __half2float(Sk[idx]);
      float sq = __half2float(Sq[idx]);
      float code1 = 16384.f * __expf(sk * 20.f) * cuk * vks[i];
      float t1 = code1 * (logB + sk * 20.f + luk + lvks[i] - sq * 10.f + lsqs[i]);
      float code2 = 16384.f * __expf(sq * 20.f) * cuq * vqs[i];
      float t2 = code2 * (logB + sq * 20.f + luq + lvqs[i] - sk * 10.f + lsks[i]);
      acc += t1 + t2;
    }
  }
  float tot = blk_sum(acc, s4);
  if (tx == 0) atomicAdd(accOut, tot);
}

__global__ void finalize_k(const float* __restrict__ acc, float* __restrict__ out) {
  out[0] = acc[0] * (1.f / 32768.f);   // /(2*B)
}

extern "C" void kernel_launch(void* const* d_in, const int* in_sizes, int n_in,
                              void* d_out, int out_size, void* d_ws, size_t ws_size,
                              hipStream_t stream) {
  const float* q = (const float*)d_in[0];
  const float* k = (const float*)d_in[1];
  const float* c = (const float*)d_in[2];
  float* out = (float*)d_out;

  char* ws = (char*)d_ws;
  // layout (bytes)
  __bf16* nq = (__bf16*)(ws);                 // 16384*256*2 = 8,388,608
  __bf16* nk = (__bf16*)(ws + 8388608);       // 8,388,608
  __bf16* nc = (__bf16*)(ws + 16777216);      // 3072*256*2  = 1,572,864
  __half* Sq = (__half*)(ws + 18350080);      // 16384*3000*2 = 98,304,000
  __half* Sk = (__half*)(ws + 116654080);     // 98,304,000
  float* fbase = (float*)(ws + 214958080);
  float* csum = fbase;                        // 3072
  float* uk   = fbase + 3072;                 // 3072
  float* uq   = fbase + 6144;                 // 3072
  float* rsum = fbase + 9216;                 // 16384
  float* vk   = fbase + 25600;                // 16384
  float* vq   = fbase + 41984;                // 16384
  float* lseq = fbase + 58368;                // 16384
  float* lsek = fbase + 74752;                // 16384
  float* accv = fbase + 91136;                // 1

  normalize_rows<<<16384, 256, 0, stream>>>(q, nq, BATCH);
  normalize_rows<<<16384, 256, 0, stream>>>(k, nk, BATCH);
  normalize_rows<<<3072, 256, 0, stream>>>(c, nc, KC);

  dim3 gg(BATCH / 128, KCPAD / 128);
  gemm_bf16<<<gg, 256, 0, stream>>>(nq, nc, Sq);
  gemm_bf16<<<gg, 256, 0, stream>>>(nk, nc, Sk);

  dim3 gcs(12, BATCH / 128);

  // sinkhorn on Sk -> uk, vk
  for (int it = 0; it < 3; ++it) {
    hipMemsetAsync(csum, 0, 3072 * sizeof(float), stream);
    colsum_exp<<<gcs, 256, 0, stream>>>(Sk, it == 0 ? nullptr : vk, csum);
    vrecip<<<12, 256, 0, stream>>>(csum, uk, KC, (float)KC);
    rowsum_exp<<<BATCH, 256, 0, stream>>>(Sk, uk, rsum);
    vrecip<<<64, 256, 0, stream>>>(rsum, vk, BATCH, (float)BATCH);
  }
  // sinkhorn on Sq -> uq, vq
  for (int it = 0; it < 3; ++it) {
    hipMemsetAsync(csum, 0, 3072 * sizeof(float), stream);
    colsum_exp<<<gcs, 256, 0, stream>>>(Sq, it == 0 ? nullptr : vq, csum);
    vrecip<<<12, 256, 0, stream>>>(csum, uq, KC, (float)KC);
    rowsum_exp<<<BATCH, 256, 0, stream>>>(Sq, uq, rsum);
    vrecip<<<64, 256, 0, stream>>>(rsum, vq, BATCH, (float)BATCH);
  }

  row_lse<<<BATCH, 256, 0, stream>>>(Sq, lseq);
  row_lse<<<BATCH, 256, 0, stream>>>(Sk, lsek);

  hipMemsetAsync(accv, 0, sizeof(float), stream);
  dim3 gkl(12, BATCH / 256);
  kl_kernel<<<gkl, 256, 0, stream>>>(Sk, Sq, uk, vk, uq, vq, lseq, lsek, accv);
  finalize_k<<<1, 1, 0, stream>>>(accv, out);
}